// Round 2
// baseline (1113.272 us; speedup 1.0000x reference)
//
#include <hip/hip_runtime.h>
#include <stdint.h>

#define DEV __device__ __forceinline__

typedef short bf16x8 __attribute__((ext_vector_type(8)));
typedef float f32x4 __attribute__((ext_vector_type(4)));

// ---------- bf16 helpers (manual, RNE) ----------
DEV ushort f2bf(float x) {
  uint32_t u = __builtin_bit_cast(uint32_t, x);
  return (ushort)((u + 0x7fffu + ((u >> 16) & 1u)) >> 16);
}
DEV float bf2f(ushort h) { return __builtin_bit_cast(float, (uint32_t)h << 16); }

// ---------- async global->LDS (16B per lane, wave-uniform LDS base) ----------
DEV void gload_lds16(const void* g, void* l) {
  __builtin_amdgcn_global_load_lds((const __attribute__((address_space(1))) uint32_t*)g,
                                   (__attribute__((address_space(3))) uint32_t*)l, 16, 0, 0);
}

// =====================================================================
// GEMM: C[M,N] = A[M,K] * W[N,K]^T  (both row-major bf16, K fast dim)
// 128x128 tile, BK=64, 256 threads = 4 waves (2x2), 64x64 per wave.
// LDS swizzle (rule #21, both sides): physical in-row byte =
//   logical ^ ((row&7)<<4); staged via LINEAR global_load_lds with
//   pre-swizzled GLOBAL source column; reads apply the same XOR.
//   -> ds_read_b128 lands 2 lanes per 16B slot per 16-lane group (free).
// EPI: 0 = bias, store f32; 1 = bias, store bf16; 2 = bias+lrelu, store bf16
// =====================================================================
template <int EPI>
__global__ __launch_bounds__(256, 2) void gemm_bt(
    const ushort* __restrict__ A, int lda, const ushort* __restrict__ W, int ldb,
    void* __restrict__ Cv, int ldc, const float* __restrict__ bias, int K) {
  __shared__ ushort As[128 * 64];
  __shared__ ushort Bs[128 * 64];
  const int t = threadIdx.x;
  const int l = t & 63;
  const int w = t >> 6;
  const int wr = w >> 1, wc = w & 1;
  const int rowBase = blockIdx.y << 7;
  const int colBase = blockIdx.x << 7;

  // staging: chunk ch = 8 rows (1024 B). lane l covers row ch*8 + (l>>3),
  // LDS bytes [ch*1024 + l*16, +16) = physical in-row byte (l&7)*16.
  // physical (l&7)*16 corresponds to logical col ((l&7)^(r&7))*16 bytes,
  // r&7 == l>>3  ->  pre-swizzled global column:
  const int cr = l >> 3;
  const int ccol = ((l & 7) ^ cr) << 3;  // in elements
  const ushort* aS = A + (size_t)(rowBase + cr) * lda + ccol;
  const ushort* bS = W + (size_t)(colBase + cr) * ldb + ccol;

  f32x4 acc[4][4] = {};

  const int nk = K >> 6;
  for (int kt = 0; kt < nk; ++kt) {
    if (kt) __syncthreads();  // all waves done reading LDS of tile kt-1
    const int k0 = kt << 6;
#pragma unroll
    for (int c4 = 0; c4 < 4; ++c4) {
      const int ch = (w << 2) + c4;  // wave-uniform chunk id
      gload_lds16(aS + (size_t)(ch << 3) * lda + k0, (char*)As + (ch << 10));
      gload_lds16(bS + (size_t)(ch << 3) * ldb + k0, (char*)Bs + (ch << 10));
    }
    __syncthreads();  // compiler drains vmcnt(0) before s_barrier -> tile visible

    // A-frag (16x16x32): lane row = l&15, k-elems = (l>>4)*8..+8 -> byte koff
    bf16x8 af[2][4], bw[2][4];
    const int koff = (l >> 4) << 4;
#pragma unroll
    for (int mi = 0; mi < 4; ++mi) {
      const int r = (wr << 6) + (mi << 4) + (l & 15);
      const char* rp = (const char*)As + (r << 7);
      const int sw = (r & 7) << 4;
      af[0][mi] = *(const bf16x8*)(rp + (koff ^ sw));
      af[1][mi] = *(const bf16x8*)(rp + ((64 + koff) ^ sw));
    }
#pragma unroll
    for (int ni = 0; ni < 4; ++ni) {
      const int r = (wc << 6) + (ni << 4) + (l & 15);
      const char* rp = (const char*)Bs + (r << 7);
      const int sw = (r & 7) << 4;
      bw[0][ni] = *(const bf16x8*)(rp + (koff ^ sw));
      bw[1][ni] = *(const bf16x8*)(rp + ((64 + koff) ^ sw));
    }
#pragma unroll
    for (int kk = 0; kk < 2; ++kk)
#pragma unroll
      for (int mi = 0; mi < 4; ++mi)
#pragma unroll
        for (int ni = 0; ni < 4; ++ni)
          acc[mi][ni] = __builtin_amdgcn_mfma_f32_16x16x32_bf16(
              af[kk][mi], bw[kk][ni], acc[mi][ni], 0, 0, 0);
  }

  // epilogue: C/D layout (m89-verified): col = l&15, row = (l>>4)*4 + j
  const int orow = (l >> 4) << 2;
  const int ocol = l & 15;
#pragma unroll
  for (int ni = 0; ni < 4; ++ni) {
    const int col = colBase + (wc << 6) + (ni << 4) + ocol;
    const float bv = bias[col];
#pragma unroll
    for (int mi = 0; mi < 4; ++mi) {
      const int row0 = rowBase + (wr << 6) + (mi << 4) + orow;
#pragma unroll
      for (int j = 0; j < 4; ++j) {
        float v = acc[mi][ni][j] + bv;
        if (EPI == 2) v = v >= 0.f ? v : 0.2f * v;
        const size_t idx = (size_t)(row0 + j) * ldc + col;
        if (EPI == 0)
          ((float*)Cv)[idx] = v;
        else
          ((ushort*)Cv)[idx] = f2bf(v);
      }
    }
  }
}

// =====================================================================
// In-place LayerNorm + LeakyReLU over rows of a bf16 [B, N] buffer.
// One block (256 thr) per row. Memory-bound: vectorized ushort4 loads.
// =====================================================================
template <int N>
__global__ __launch_bounds__(256) void ln_lrelu(ushort* __restrict__ buf,
                                                const float* __restrict__ g,
                                                const float* __restrict__ b) {
  constexpr int E = N / 256;
  const int t = threadIdx.x;
  ushort* p = buf + (size_t)blockIdx.x * N + t * E;
  ushort us[E];
  *(ushort4*)&us[0] = *(const ushort4*)p;
  if constexpr (E == 8) *(ushort4*)&us[4] = *(const ushort4*)(p + 4);
  float f[E], s = 0.f, sq = 0.f;
#pragma unroll
  for (int j = 0; j < E; ++j) {
    f[j] = bf2f(us[j]);
    s += f[j];
    sq += f[j] * f[j];
  }
#pragma unroll
  for (int d = 32; d; d >>= 1) {
    s += __shfl_xor(s, d);
    sq += __shfl_xor(sq, d);
  }
  __shared__ float red[8];
  if ((t & 63) == 0) {
    red[(t >> 6) * 2] = s;
    red[(t >> 6) * 2 + 1] = sq;
  }
  __syncthreads();
  s = red[0] + red[2] + red[4] + red[6];
  sq = red[1] + red[3] + red[5] + red[7];
  const float mean = s * (1.f / N);
  const float rstd = rsqrtf(sq * (1.f / N) - mean * mean + 1e-5f);
  const float* gp = g + t * E;
  const float* bp = b + t * E;
#pragma unroll
  for (int j = 0; j < E; ++j) {
    float y = (f[j] - mean) * rstd * gp[j] + bp[j];
    y = y >= 0.f ? y : 0.2f * y;
    us[j] = f2bf(y);
  }
  *(ushort4*)p = *(ushort4*)&us[0];
  if constexpr (E == 8) *(ushort4*)(p + 4) = *(ushort4*)&us[4];
}

// =====================================================================
// z = mu + eps*exp(0.5*lv); attn = softmax(z @ ctx^T); z_enh = z + 0.1*attn@ctx
// ctx [32,256] f32 (32KB) -> LDS (row pad +1 vs bank conflict).
// One wave per batch row; 1024 blocks x 4 waves x 8 iters = 32768 rows.
// =====================================================================
__global__ __launch_bounds__(256) void reparam_attn(
    const float* __restrict__ mu, const float* __restrict__ lv,
    const float* __restrict__ eps, const float* __restrict__ ctx,
    ushort* __restrict__ zb) {
  __shared__ float ctx_lds[32][257];
  __shared__ float z_lds[4][256];
  __shared__ float w_lds[4][32];
  const int t = threadIdx.x;
  for (int i = t; i < 32 * 256; i += 256) ctx_lds[i >> 8][i & 255] = ctx[i];
  __syncthreads();
  const int l = t & 63, wv = t >> 6;
  const int gw = blockIdx.x * 4 + wv;  // 0..4095
  const int m = l & 31, half = l >> 5;
  for (int it = 0; it < 8; ++it) {
    const int r = gw + 4096 * it;
    const size_t base = (size_t)r * 256;
    float z[4];
#pragma unroll
    for (int j = 0; j < 4; ++j) {
      const int c = l + 64 * j;
      z[j] = mu[base + c] + eps[base + c] * __expf(0.5f * lv[base + c]);
      z_lds[wv][c] = z[j];
    }
    __syncthreads();
    // lane l: dot(ctx row m=l&31, z[half*128 .. +128))
    float s = 0.f;
#pragma unroll 4
    for (int i2 = 0; i2 < 128; ++i2) {
      const int c = half * 128 + i2;
      s += ctx_lds[m][c] * z_lds[wv][c];
    }
    s += __shfl_xor(s, 32);  // both halves now hold full dot for row m
    float mx = s;
#pragma unroll
    for (int d2 = 16; d2; d2 >>= 1) mx = fmaxf(mx, __shfl_xor(mx, d2));
    const float e = __expf(s - mx);
    float sm = e;
#pragma unroll
    for (int d2 = 16; d2; d2 >>= 1) sm += __shfl_xor(sm, d2);
    w_lds[wv][m] = e / sm;  // lanes l and l^32 write identical value
    __syncthreads();
#pragma unroll
    for (int j = 0; j < 4; ++j) {
      const int c = l + 64 * j;
      float a = 0.f;
#pragma unroll 8
      for (int mm = 0; mm < 32; ++mm) a += w_lds[wv][mm] * ctx_lds[mm][c];
      zb[base + c] = f2bf(z[j] + 0.1f * a);
    }
    __syncthreads();
  }
}

// ---------- f32 -> bf16 conversion for x + 8 weight tensors ----------
struct ConvArgs {
  const float* src[9];
  ushort* dst[9];
  int n4[9];
};
__global__ __launch_bounds__(256) void conv_bf16(ConvArgs a) {
  const int y = blockIdx.y;
  const float4* s = (const float4*)a.src[y];
  ushort4* d = (ushort4*)a.dst[y];
  const int n4 = a.n4[y];
  const int stride = gridDim.x * 256;
  for (int i = blockIdx.x * 256 + threadIdx.x; i < n4; i += stride) {
    float4 v = s[i];
    ushort4 o;
    o.x = f2bf(v.x); o.y = f2bf(v.y); o.z = f2bf(v.z); o.w = f2bf(v.w);
    d[i] = o;
  }
}

// =====================================================================
// Host side
// =====================================================================
extern "C" void kernel_launch(void* const* d_in, const int* in_sizes, int n_in,
                              void* d_out, int out_size, void* d_ws, size_t ws_size,
                              hipStream_t stream) {
  constexpr size_t NB = 32768, ND = 768, NL = 256;

  const float* x = (const float*)d_in[0];
  const float* eps = (const float*)d_in[1];

  char* ws = (char*)d_ws;
  // Workspace live-range plan (total 216.0 MB):
  //  [0,      67.1M)  XB (x bf16, 50.3M; dead after G1) then T1
  //  [67.1M, 134.2M)  T2;  T3 spans [67.1M, 201.3M) (T2 dead at dec2)
  //  [134.2M,201.3M)  ZB (16.8M; dead before dec2 overwrites via T3)
  //  [201.3M,216.0M)  weights (live to the end)
  ushort* XB = (ushort*)(ws + 0);
  ushort* T1 = (ushort*)(ws + 0);
  ushort* T2 = (ushort*)(ws + 67108864ull);
  ushort* T3 = (ushort*)(ws + 67108864ull);
  ushort* ZB = (ushort*)(ws + 134217728ull);
  ushort* WB = (ushort*)(ws + 201326592ull);

  ushort* w1 = WB;               // [1024,768]
  ushort* w2 = w1 + 786432;      // [1024,1024]
  ushort* wmu = w2 + 1048576;    // [256,1024]
  ushort* wlv = wmu + 262144;    // [256,1024]
  ushort* wdi = wlv + 262144;    // [1024,256]
  ushort* wd1 = wdi + 262144;    // [1024,1024]
  ushort* wd2 = wd1 + 1048576;   // [2048,1024]
  ushort* wd3 = wd2 + 2097152;   // [768,2048]

  ConvArgs ca;
  ca.src[0] = x;                      ca.dst[0] = XB;  ca.n4[0] = (int)(NB * ND / 4);
  ca.src[1] = (const float*)d_in[2];  ca.dst[1] = w1;  ca.n4[1] = 786432 / 4;
  ca.src[2] = (const float*)d_in[6];  ca.dst[2] = w2;  ca.n4[2] = 1048576 / 4;
  ca.src[3] = (const float*)d_in[10]; ca.dst[3] = wmu; ca.n4[3] = 262144 / 4;
  ca.src[4] = (const float*)d_in[12]; ca.dst[4] = wlv; ca.n4[4] = 262144 / 4;
  ca.src[5] = (const float*)d_in[14]; ca.dst[5] = wdi; ca.n4[5] = 262144 / 4;
  ca.src[6] = (const float*)d_in[16]; ca.dst[6] = wd1; ca.n4[6] = 1048576 / 4;
  ca.src[7] = (const float*)d_in[20]; ca.dst[7] = wd2; ca.n4[7] = 2097152 / 4;
  ca.src[8] = (const float*)d_in[24]; ca.dst[8] = wd3; ca.n4[8] = 1572864 / 4;
  conv_bf16<<<dim3(1024, 9), 256, 0, stream>>>(ca);

  float* out = (float*)d_out;
  float* mu_o = out + NB * ND;
  float* lv_o = mu_o + NB * NL;

  // encoder
  gemm_bt<1><<<dim3(8, 256), 256, 0, stream>>>(XB, 768, w1, 768, T2, 1024,
                                               (const float*)d_in[3], 768);
  ln_lrelu<1024><<<32768, 256, 0, stream>>>(T2, (const float*)d_in[4], (const float*)d_in[5]);
  gemm_bt<1><<<dim3(8, 256), 256, 0, stream>>>(T2, 1024, w2, 1024, T1, 1024,
                                               (const float*)d_in[7], 1024);
  ln_lrelu<1024><<<32768, 256, 0, stream>>>(T1, (const float*)d_in[8], (const float*)d_in[9]);
  // mu / logvar -> fp32 outputs
  gemm_bt<0><<<dim3(2, 256), 256, 0, stream>>>(T1, 1024, wmu, 1024, mu_o, 256,
                                               (const float*)d_in[11], 1024);
  gemm_bt<0><<<dim3(2, 256), 256, 0, stream>>>(T1, 1024, wlv, 1024, lv_o, 256,
                                               (const float*)d_in[13], 1024);
  // reparameterize + context attention -> z_enh (bf16)
  reparam_attn<<<1024, 256, 0, stream>>>(mu_o, lv_o, eps, (const float*)d_in[26], ZB);
  // decoder
  gemm_bt<2><<<dim3(8, 256), 256, 0, stream>>>(ZB, 256, wdi, 256, T2, 1024,
                                               (const float*)d_in[15], 256);
  gemm_bt<1><<<dim3(8, 256), 256, 0, stream>>>(T2, 1024, wd1, 1024, T1, 1024,
                                               (const float*)d_in[17], 1024);
  ln_lrelu<1024><<<32768, 256, 0, stream>>>(T1, (const float*)d_in[18], (const float*)d_in[19]);
  gemm_bt<1><<<dim3(16, 256), 256, 0, stream>>>(T1, 1024, wd2, 1024, T3, 2048,
                                                (const float*)d_in[21], 1024);
  ln_lrelu<2048><<<32768, 256, 0, stream>>>(T3, (const float*)d_in[22], (const float*)d_in[23]);
  gemm_bt<0><<<dim3(6, 256), 256, 0, stream>>>(T3, 2048, wd3, 2048, out, 768,
                                               (const float*)d_in[25], 2048);
}

// Round 3
// 1110.693 us; speedup vs baseline: 1.0023x; 1.0023x over previous
//
#include <hip/hip_runtime.h>
#include <stdint.h>

#define DEV __device__ __forceinline__

typedef short bf16x8 __attribute__((ext_vector_type(8)));
typedef float f32x4 __attribute__((ext_vector_type(4)));

// ---------- bf16 helpers (manual, RNE) ----------
DEV ushort f2bf(float x) {
  uint32_t u = __builtin_bit_cast(uint32_t, x);
  return (ushort)((u + 0x7fffu + ((u >> 16) & 1u)) >> 16);
}
DEV float bf2f(ushort h) { return __builtin_bit_cast(float, (uint32_t)h << 16); }

// ---------- async global->LDS (16B per lane, wave-uniform LDS base) ----------
DEV void gload_lds16(const void* g, void* l) {
  __builtin_amdgcn_global_load_lds((const __attribute__((address_space(1))) uint32_t*)g,
                                   (__attribute__((address_space(3))) uint32_t*)l, 16, 0, 0);
}

DEV bf16x8 ldv(const void* p) { return *(const bf16x8*)p; }

#define BARRIER __builtin_amdgcn_s_barrier()
#define SCHED0 __builtin_amdgcn_sched_barrier(0)
#define PRIO1 __builtin_amdgcn_s_setprio(1)
#define PRIO0 __builtin_amdgcn_s_setprio(0)
#define LGKM0                                        \
  do {                                               \
    asm volatile("s_waitcnt lgkmcnt(0)" ::: "memory"); \
    SCHED0;                                          \
  } while (0)

#define MFMA16(MH, NH, F, Bq)                                                   \
  _Pragma("unroll") for (int mi = 0; mi < 4; ++mi) {                            \
    _Pragma("unroll") for (int ni = 0; ni < 2; ++ni) {                          \
      acc[(MH)*4 + mi][(NH)*2 + ni] = __builtin_amdgcn_mfma_f32_16x16x32_bf16(  \
          F[mi][0], Bq[ni][0], acc[(MH)*4 + mi][(NH)*2 + ni], 0, 0, 0);         \
      acc[(MH)*4 + mi][(NH)*2 + ni] = __builtin_amdgcn_mfma_f32_16x16x32_bf16(  \
          F[mi][1], Bq[ni][1], acc[(MH)*4 + mi][(NH)*2 + ni], 0, 0, 0);         \
    }                                                                           \
  }

// =====================================================================
// 256x256 tile GEMM, BK=64, 512 thr = 8 waves (2M x 4N), 128x64 per wave.
// C[M,N] = A[M,K] * W[N,K]^T, both row-major bf16, K fast.
// 4-phase/K-tile counted-vmcnt schedule (T2+T3+T4+T5):
//   per wave, per tile: stage slots [ph1: A-mh0 x2][ph2: B x2][ph3: B x2]
//   [ph4: A-mh1 x2] of tile kt+1 into buf (kt+1)&1; each wave stages ONLY
//   half-tiles it consumes (A-half wm, B-half wn>>1), so its own vmcnt
//   gates its own data and the barrier publishes cross-wave.
//   Gates: end-ph2 vmcnt(4) [publishes A-mh1 of current tile before ph3],
//          end-ph4 vmcnt(2) [publishes A-mh0 + all B of next tile].
//   Last tile: vmcnt(0) at end-ph2 (drain 2->0). Never 0 mid-loop.
// LDS swizzle (verified 0 conflicts in R2): phys in-row byte =
//   logical ^ ((row&7)<<4); linear gload_lds dest + pre-swizzled global src.
// EPI: 0 f32; 1 bf16; 2 bf16+lrelu; 3 f32 split (mu/lv concat weight)
// =====================================================================
template <int EPI>
__global__ __launch_bounds__(512, 2) void g256(
    const ushort* __restrict__ A, int lda, const ushort* __restrict__ W, int ldb,
    void* __restrict__ Cv, long ldc, const float* __restrict__ bias,
    const float* __restrict__ bias2, long splitStride, int K) {
  __shared__ ushort As[2][256 * 64];  // 64 KB
  __shared__ ushort Bs[2][256 * 64];  // 64 KB
  const int t = threadIdx.x;
  const int l = t & 63;
  const int w = t >> 6;
  const int wm = w >> 2, wn = w & 3;

  // XCD-aware bijective swizzle (all grids divisible by 8)
  const int nwg = gridDim.x * gridDim.y;
  int bid = blockIdx.y * gridDim.x + blockIdx.x;
  const int cpx = nwg >> 3;
  bid = (bid & 7) * cpx + (bid >> 3);
  const int bx = bid % gridDim.x;
  const int by = bid / gridDim.x;
  const long rowBase = (long)by << 8;
  const int colBase = bx << 8;

  // staging lane geometry: chunk = 8 rows x 64 cols (1 KB). lane l covers
  // row ch*8 + (l>>3), phys slot l&7 -> pre-swizzled logical col:
  const int srow = l >> 3;
  const int scol = ((l & 7) ^ srow) << 3;
  const ushort* aB = A + (size_t)(rowBase + srow) * lda + scol;
  const ushort* bB = W + (size_t)(colBase + srow) * ldb + scol;
  // per-wave chunk assignments (wave stages only what it consumes)
  const int aC0 = wm * 16 + wn * 2;                        // ph1: aC0, aC0+1
  const int aC2 = aC0 + 8;                                 // ph4: aC2, aC2+1
  const int bC0 = (wn >> 1) * 16 + (wm * 2 + (wn & 1)) * 4;  // ph2/ph3: bC0..+3

  // fragment read offsets (lane-constant; r&7 == l&7 for all frag rows)
  const int fro = l & 15;
  const int o0 = (((l >> 4) << 4)) ^ ((l & 7) << 4);
  const int o1 = (64 + ((l >> 4) << 4)) ^ ((l & 7) << 4);

#define STG_A(KT1, CH) \
  gload_lds16(aB + (size_t)((CH) << 3) * lda + ((size_t)(KT1) << 6), \
              (char*)As[(KT1) & 1] + ((CH) << 10))
#define STG_B(KT1, CH) \
  gload_lds16(bB + (size_t)((CH) << 3) * ldb + ((size_t)(KT1) << 6), \
              (char*)Bs[(KT1) & 1] + ((CH) << 10))

  // ---- prologue: stage tile 0 in slot order; leave A-mh1 in flight ----
  STG_A(0, aC0); STG_A(0, aC0 + 1);
  STG_B(0, bC0); STG_B(0, bC0 + 1); STG_B(0, bC0 + 2); STG_B(0, bC0 + 3);
  STG_A(0, aC2); STG_A(0, aC2 + 1);
  asm volatile("s_waitcnt vmcnt(2)" ::: "memory");
  BARRIER;

  const int nk = K >> 6;
  f32x4 acc[8][4] = {};
  bf16x8 af[4][2], b0[2][2], b1[2][2];

  for (int kt = 0; kt < nk; ++kt) {
    const int p = kt & 1;
    const bool stage = (kt + 1) < nk;
    const int kt1 = kt + 1;
    const char* Ap = (const char*)As[p] + (wm * 128 + fro) * 128;
    const char* Bp = (const char*)Bs[p] + (wn * 64 + fro) * 128;

    // ---------- ph1: read A-mh0 + B-nh0 ; stage A-mh0(kt+1) ----------
#pragma unroll
    for (int mi = 0; mi < 4; ++mi) {
      af[mi][0] = ldv(Ap + mi * 2048 + o0);
      af[mi][1] = ldv(Ap + mi * 2048 + o1);
    }
#pragma unroll
    for (int ni = 0; ni < 2; ++ni) {
      b0[ni][0] = ldv(Bp + ni * 2048 + o0);
      b0[ni][1] = ldv(Bp + ni * 2048 + o1);
    }
    if (stage) { STG_A(kt1, aC0); STG_A(kt1, aC0 + 1); }
    BARRIER;
    LGKM0;
    PRIO1;
    MFMA16(0, 0, af, b0);
    SCHED0;
    PRIO0;
    BARRIER;

    // ---------- ph2: read B-nh1 ; stage B pair 1 ----------
#pragma unroll
    for (int ni = 0; ni < 2; ++ni) {
      b1[ni][0] = ldv(Bp + 4096 + ni * 2048 + o0);
      b1[ni][1] = ldv(Bp + 4096 + ni * 2048 + o1);
    }
    if (stage) { STG_B(kt1, bC0); STG_B(kt1, bC0 + 1); }
    BARRIER;
    LGKM0;
    PRIO1;
    MFMA16(0, 1, af, b1);
    SCHED0;
    PRIO0;
    if (stage) asm volatile("s_waitcnt vmcnt(4)" ::: "memory");
    else       asm volatile("s_waitcnt vmcnt(0)" ::: "memory");
    BARRIER;

    // ---------- ph3: read A-mh1 ; stage B pair 2 ----------
#pragma unroll
    for (int mi = 0; mi < 4; ++mi) {
      af[mi][0] = ldv(Ap + 8192 + mi * 2048 + o0);
      af[mi][1] = ldv(Ap + 8192 + mi * 2048 + o1);
    }
    if (stage) { STG_B(kt1, bC0 + 2); STG_B(kt1, bC0 + 3); }
    BARRIER;
    LGKM0;
    PRIO1;
    MFMA16(1, 1, af, b1);
    SCHED0;
    PRIO0;
    BARRIER;

    // ---------- ph4: no reads (b0 held in regs) ; stage A-mh1 ----------
    if (stage) { STG_A(kt1, aC2); STG_A(kt1, aC2 + 1); }
    BARRIER;
    SCHED0;
    PRIO1;
    MFMA16(1, 0, af, b0);
    SCHED0;
    PRIO0;
    if (stage) asm volatile("s_waitcnt vmcnt(2)" ::: "memory");
    BARRIER;
  }
#undef STG_A
#undef STG_B

  // ---------- epilogue: C/D layout col = l&15, row = (l>>4)*4 + j ----------
  const int orow = (l >> 4) << 2;
  const int ocol = l & 15;
#pragma unroll
  for (int ni = 0; ni < 4; ++ni) {
    const int col = colBase + wn * 64 + ni * 16 + ocol;
    float bv;
    if (EPI == 3)
      bv = (col < 256) ? bias[col] : bias2[col - 256];
    else
      bv = bias[col];
#pragma unroll
    for (int mi = 0; mi < 8; ++mi) {
      const long row0 = rowBase + wm * 128 + mi * 16 + orow;
#pragma unroll
      for (int j = 0; j < 4; ++j) {
        float v = acc[mi][ni][j] + bv;
        if (EPI == 2) v = v >= 0.f ? v : 0.2f * v;
        if (EPI == 0) {
          ((float*)Cv)[(row0 + j) * ldc + col] = v;
        } else if (EPI == 3) {
          const long idx = (row0 + j) * 256 + (col & 255) + (long)(col >> 8) * splitStride;
          ((float*)Cv)[idx] = v;
        } else {
          ((ushort*)Cv)[(row0 + j) * ldc + col] = f2bf(v);
        }
      }
    }
  }
}

// =====================================================================
// In-place LayerNorm + LeakyReLU over rows of a bf16 [B, N] buffer.
// =====================================================================
template <int N>
__global__ __launch_bounds__(256) void ln_lrelu(ushort* __restrict__ buf,
                                                const float* __restrict__ g,
                                                const float* __restrict__ b) {
  constexpr int E = N / 256;
  const int t = threadIdx.x;
  ushort* p = buf + (size_t)blockIdx.x * N + t * E;
  ushort us[E];
  *(ushort4*)&us[0] = *(const ushort4*)p;
  if constexpr (E == 8) *(ushort4*)&us[4] = *(const ushort4*)(p + 4);
  float f[E], s = 0.f, sq = 0.f;
#pragma unroll
  for (int j = 0; j < E; ++j) {
    f[j] = bf2f(us[j]);
    s += f[j];
    sq += f[j] * f[j];
  }
#pragma unroll
  for (int d = 32; d; d >>= 1) {
    s += __shfl_xor(s, d);
    sq += __shfl_xor(sq, d);
  }
  __shared__ float red[8];
  if ((t & 63) == 0) {
    red[(t >> 6) * 2] = s;
    red[(t >> 6) * 2 + 1] = sq;
  }
  __syncthreads();
  s = red[0] + red[2] + red[4] + red[6];
  sq = red[1] + red[3] + red[5] + red[7];
  const float mean = s * (1.f / N);
  const float rstd = rsqrtf(sq * (1.f / N) - mean * mean + 1e-5f);
  const float* gp = g + t * E;
  const float* bp = b + t * E;
#pragma unroll
  for (int j = 0; j < E; ++j) {
    float y = (f[j] - mean) * rstd * gp[j] + bp[j];
    y = y >= 0.f ? y : 0.2f * y;
    us[j] = f2bf(y);
  }
  *(ushort4*)p = *(ushort4*)&us[0];
  if constexpr (E == 8) *(ushort4*)(p + 4) = *(ushort4*)&us[4];
}

// =====================================================================
// z = mu + eps*exp(0.5*lv); attn = softmax(z @ ctx^T); z_enh = z + 0.1*attn@ctx
// =====================================================================
__global__ __launch_bounds__(256) void reparam_attn(
    const float* __restrict__ mu, const float* __restrict__ lv,
    const float* __restrict__ eps, const float* __restrict__ ctx,
    ushort* __restrict__ zb) {
  __shared__ float ctx_lds[32][257];
  __shared__ float z_lds[4][256];
  __shared__ float w_lds[4][32];
  const int t = threadIdx.x;
  for (int i = t; i < 32 * 256; i += 256) ctx_lds[i >> 8][i & 255] = ctx[i];
  __syncthreads();
  const int l = t & 63, wv = t >> 6;
  const int gw = blockIdx.x * 4 + wv;
  const int m = l & 31, half = l >> 5;
  for (int it = 0; it < 8; ++it) {
    const int r = gw + 4096 * it;
    const size_t base = (size_t)r * 256;
    float z[4];
#pragma unroll
    for (int j = 0; j < 4; ++j) {
      const int c = l + 64 * j;
      z[j] = mu[base + c] + eps[base + c] * __expf(0.5f * lv[base + c]);
      z_lds[wv][c] = z[j];
    }
    __syncthreads();
    float s = 0.f;
#pragma unroll 4
    for (int i2 = 0; i2 < 128; ++i2) {
      const int c = half * 128 + i2;
      s += ctx_lds[m][c] * z_lds[wv][c];
    }
    s += __shfl_xor(s, 32);
    float mx = s;
#pragma unroll
    for (int d2 = 16; d2; d2 >>= 1) mx = fmaxf(mx, __shfl_xor(mx, d2));
    const float e = __expf(s - mx);
    float sm = e;
#pragma unroll
    for (int d2 = 16; d2; d2 >>= 1) sm += __shfl_xor(sm, d2);
    w_lds[wv][m] = e / sm;
    __syncthreads();
#pragma unroll
    for (int j = 0; j < 4; ++j) {
      const int c = l + 64 * j;
      float a = 0.f;
#pragma unroll 8
      for (int mm = 0; mm < 32; ++mm) a += w_lds[wv][mm] * ctx_lds[mm][c];
      zb[base + c] = f2bf(z[j] + 0.1f * a);
    }
    __syncthreads();
  }
}

// ---------- f32 -> bf16 conversion for x + 8 weight tensors ----------
struct ConvArgs {
  const float* src[9];
  ushort* dst[9];
  int n4[9];
};
__global__ __launch_bounds__(256) void conv_bf16(ConvArgs a) {
  const int y = blockIdx.y;
  const float4* s = (const float4*)a.src[y];
  ushort4* d = (ushort4*)a.dst[y];
  const int n4 = a.n4[y];
  const int stride = gridDim.x * 256;
  for (int i = blockIdx.x * 256 + threadIdx.x; i < n4; i += stride) {
    float4 v = s[i];
    ushort4 o;
    o.x = f2bf(v.x); o.y = f2bf(v.y); o.z = f2bf(v.z); o.w = f2bf(v.w);
    d[i] = o;
  }
}

// =====================================================================
// Host side
// =====================================================================
extern "C" void kernel_launch(void* const* d_in, const int* in_sizes, int n_in,
                              void* d_out, int out_size, void* d_ws, size_t ws_size,
                              hipStream_t stream) {
  constexpr size_t NB = 32768, ND = 768, NL = 256;

  const float* x = (const float*)d_in[0];
  const float* eps = (const float*)d_in[1];

  char* ws = (char*)d_ws;
  // Workspace live-range plan (total 216.0 MB):
  //  [0,      67.1M)  XB (x bf16; dead after enc1) then T1
  //  [67.1M, 134.2M)  T2;  T3 spans [67.1M, 201.3M) (T2 dead at dec2)
  //  [134.2M,201.3M)  ZB (16.8M; consumed by di before dec2 overwrites)
  //  [201.3M,216.0M)  weights (live to the end); wmu+wlv adjacent = [512,1024]
  ushort* XB = (ushort*)(ws + 0);
  ushort* T1 = (ushort*)(ws + 0);
  ushort* T2 = (ushort*)(ws + 67108864ull);
  ushort* T3 = (ushort*)(ws + 67108864ull);
  ushort* ZB = (ushort*)(ws + 134217728ull);
  ushort* WB = (ushort*)(ws + 201326592ull);

  ushort* w1 = WB;               // [1024,768]
  ushort* w2 = w1 + 786432;      // [1024,1024]
  ushort* wmu = w2 + 1048576;    // [256,1024]  (wlv adjacent -> [512,1024])
  ushort* wlv = wmu + 262144;    // [256,1024]
  ushort* wdi = wlv + 262144;    // [1024,256]
  ushort* wd1 = wdi + 262144;    // [1024,1024]
  ushort* wd2 = wd1 + 1048576;   // [2048,1024]
  ushort* wd3 = wd2 + 2097152;   // [768,2048]

  ConvArgs ca;
  ca.src[0] = x;                      ca.dst[0] = XB;  ca.n4[0] = (int)(NB * ND / 4);
  ca.src[1] = (const float*)d_in[2];  ca.dst[1] = w1;  ca.n4[1] = 786432 / 4;
  ca.src[2] = (const float*)d_in[6];  ca.dst[2] = w2;  ca.n4[2] = 1048576 / 4;
  ca.src[3] = (const float*)d_in[10]; ca.dst[3] = wmu; ca.n4[3] = 262144 / 4;
  ca.src[4] = (const float*)d_in[12]; ca.dst[4] = wlv; ca.n4[4] = 262144 / 4;
  ca.src[5] = (const float*)d_in[14]; ca.dst[5] = wdi; ca.n4[5] = 262144 / 4;
  ca.src[6] = (const float*)d_in[16]; ca.dst[6] = wd1; ca.n4[6] = 1048576 / 4;
  ca.src[7] = (const float*)d_in[20]; ca.dst[7] = wd2; ca.n4[7] = 2097152 / 4;
  ca.src[8] = (const float*)d_in[24]; ca.dst[8] = wd3; ca.n4[8] = 1572864 / 4;
  conv_bf16<<<dim3(1024, 9), 256, 0, stream>>>(ca);

  float* out = (float*)d_out;
  float* mu_o = out + NB * ND;
  float* lv_o = mu_o + NB * NL;

  const long SPLIT = (long)NB * 256;

  // encoder
  g256<1><<<dim3(4, 128), 512, 0, stream>>>(XB, 768, w1, 768, T2, 1024,
                                            (const float*)d_in[3], nullptr, 0, 768);
  ln_lrelu<1024><<<32768, 256, 0, stream>>>(T2, (const float*)d_in[4], (const float*)d_in[5]);
  g256<1><<<dim3(4, 128), 512, 0, stream>>>(T2, 1024, w2, 1024, T1, 1024,
                                            (const float*)d_in[7], nullptr, 0, 1024);
  ln_lrelu<1024><<<32768, 256, 0, stream>>>(T1, (const float*)d_in[8], (const float*)d_in[9]);
  // mu & logvar in one GEMM (concat weight [512,1024]) -> split fp32 outputs
  g256<3><<<dim3(2, 128), 512, 0, stream>>>(T1, 1024, wmu, 1024, mu_o, 256,
                                            (const float*)d_in[11], (const float*)d_in[13],
                                            SPLIT, 1024);
  // reparameterize + context attention -> z_enh (bf16)
  reparam_attn<<<1024, 256, 0, stream>>>(mu_o, lv_o, eps, (const float*)d_in[26], ZB);
  // decoder
  g256<2><<<dim3(4, 128), 512, 0, stream>>>(ZB, 256, wdi, 256, T2, 1024,
                                            (const float*)d_in[15], nullptr, 0, 256);
  g256<1><<<dim3(4, 128), 512, 0, stream>>>(T2, 1024, wd1, 1024, T1, 1024,
                                            (const float*)d_in[17], nullptr, 0, 1024);
  ln_lrelu<1024><<<32768, 256, 0, stream>>>(T1, (const float*)d_in[18], (const float*)d_in[19]);
  g256<1><<<dim3(8, 128), 512, 0, stream>>>(T1, 1024, wd2, 1024, T3, 2048,
                                            (const float*)d_in[21], nullptr, 0, 1024);
  ln_lrelu<2048><<<32768, 256, 0, stream>>>(T3, (const float*)d_in[22], (const float*)d_in[23]);
  g256<0><<<dim3(3, 128), 512, 0, stream>>>(T3, 2048, wd3, 2048, out, 768,
                                            (const float*)d_in[25], nullptr, 0, 2048);
}